// Round 5
// baseline (714.200 us; speedup 1.0000x reference)
//
#include <hip/hip_runtime.h>
#include <cmath>

#define B_   2
#define S_   2048
#define H_   2304
#define NH_  8
#define HD_  256
#define NKV_ 4
#define WIN_ 512
#define QKVW 4096   // fused QKV output row width (8+4+4 heads * 256)

typedef unsigned short ushort_t;
typedef __attribute__((ext_vector_type(8))) short bf16x8;     // 8 bf16 = 4 VGPRs
typedef __attribute__((ext_vector_type(4))) float floatx4;

// round-to-nearest-even fp32 -> bf16
__device__ __forceinline__ unsigned short f2bf(float f) {
  unsigned u = __builtin_bit_cast(unsigned, f);
  u += 0x7fff + ((u >> 16) & 1);
  return (unsigned short)(u >> 16);
}
__device__ __forceinline__ float bf2f(ushort_t v) {
  unsigned u = (unsigned)v << 16;
  return __builtin_bit_cast(float, u);
}

// async global->LDS, 16 B per lane. LDS dest = wave-uniform base + lane*16.
__device__ __forceinline__ void gl2lds16(const void* g, void* l) {
  __builtin_amdgcn_global_load_lds(
      (const __attribute__((address_space(1))) unsigned int*)g,
      (__attribute__((address_space(3))) unsigned int*)l, 16, 0, 0);
}

// ---------------------------------------------------------------------------
// Elementwise fp32 -> bf16 cast (4 elems/thread).
// ---------------------------------------------------------------------------
__global__ void cast_bf16(const float* __restrict__ in, ushort_t* __restrict__ out) {
  const int i = blockIdx.x * 256 + threadIdx.x;
  float4 v = ((const float4*)in)[i];
  ushort4 o;
  o.x = f2bf(v.x); o.y = f2bf(v.y); o.z = f2bf(v.z); o.w = f2bf(v.w);
  ((ushort4*)out)[i] = o;
}

// ---------------------------------------------------------------------------
// W[K,N] fp32 -> Wt[N,K] bf16 (32x32 LDS tiles, 256 threads).
// ---------------------------------------------------------------------------
__global__ void transpose_cast(const float* __restrict__ W, ushort_t* __restrict__ Wt,
                               int K, int N) {
  __shared__ float t[32][33];
  const int lx = threadIdx.x & 31, ly = threadIdx.x >> 5;   // ly 0..7
  const int n0 = blockIdx.x * 32, k0 = blockIdx.y * 32;
#pragma unroll
  for (int i = 0; i < 4; ++i)
    t[ly + i * 8][lx] = W[(long long)(k0 + ly + i * 8) * N + n0 + lx];
  __syncthreads();
#pragma unroll
  for (int i = 0; i < 4; ++i)
    Wt[(long long)(n0 + ly + i * 8) * K + k0 + lx] = f2bf(t[lx][ly + i * 8]);
}

// ===========================================================================
// 256x256-tile bf16 MFMA GEMM, v5: WAVE-GROUP-STAGGERED, tri-buffered BK=32.
//   C[M,N] = A[M,K] @ Bt[N,K]^T      (requires K % 96 == 0 -> NT % 3 == 0)
// 512 threads = 8 waves (2M x 4N), per-wave 128x64 (acc[8][4]).
// LDS: 3 buffers x (A 256x32 + B 256x32) = 96 KiB dynamic. global_load_lds
// width=16, chunk^(row&3) swizzle via pre-swizzled GLOBAL source.
//
// WHY: r1/r2/r4 all serialized LDS and MFMA pipes (MfmaUtil 40%): all 8
// waves ran identical phase orders in lockstep, so every wave stalled on
// the same resource simultaneously. v5 creates the role-split:
//   waves 0-3 (wm=0):   quadrants (0,0)->(0,1)->(1,1)->(1,0)
//   waves 4-7 (wm=128): quadrants (1,1)->(1,0)->(0,0)->(0,1)
// On each SIMD (pairs w,w+4) one wave issues MFMAs while the other reads;
// setprio(1) on MFMA clusters lets the scheduler prefer the MFMA wave (T5).
//
// Per K-tile (32-K): 4 phases x 8 MFMA; ONE barrier. Tri-buffer horizon:
// tile t+1's stages (issued during t-1, front-loaded ph1-2) are drained by
// t-1's end vmcnt(0)+barrier => during tile t, cross-tile reads of buffer
// t+1 are race-free. Stages write buffer t+2 whose old contents (t-1) were
// fully consumed before t-1's end barrier => no WAR window.
//
// Register sets aP,aQ (16 VGPR), bP,bQ (8): reload only after last MFMA use
// (death-checked per phase, both orders); reads issued >=1 phase before
// their consuming MFMA; compiler emits counted lgkm waits.
// ===========================================================================
#define RA32(dst_, base_, qm_) do { \
  _Pragma("unroll") for (int i_ = 0; i_ < 4; ++i_) { \
    const int row_ = wm + (qm_) * 64 + i_ * 16 + l15; \
    dst_[i_] = *(const bf16x8*)&(base_)[row_ * 32 + ((lq ^ (row_ & 3)) * 8)]; \
  } \
} while (0)

#define RB32(dst_, base_, qn_) do { \
  _Pragma("unroll") for (int j_ = 0; j_ < 2; ++j_) { \
    const int row_ = wn + (qn_) * 32 + j_ * 16 + l15; \
    dst_[j_] = *(const bf16x8*)&(base_)[row_ * 32 + ((lq ^ (row_ & 3)) * 8)]; \
  } \
} while (0)

#define MFMA8(qm_, qn_, as_, bs_) do { \
  __builtin_amdgcn_s_setprio(1); \
  _Pragma("unroll") for (int i_ = 0; i_ < 4; ++i_) \
  _Pragma("unroll") for (int j_ = 0; j_ < 2; ++j_) \
    acc[(qm_) * 4 + i_][(qn_) * 2 + j_] = __builtin_amdgcn_mfma_f32_16x16x32_bf16( \
        as_[i_], bs_[j_], acc[(qm_) * 4 + i_][(qn_) * 2 + j_], 0, 0, 0); \
  __builtin_amdgcn_s_setprio(0); \
} while (0)

// stage one 128-row x 32-col half-tile (8 KB): 1 gl2lds per lane.
// wave w covers rows [hf*128 + w*16, +16); lane: row += l>>2, chunk (l&3)^rowkey.
#define STG32(dst_, gsrc_, t_, hf_) do { \
  const int r0_ = (hf_) * 128 + w * 16; \
  gl2lds16(gsrc_ + (size_t)r0_ * K + (size_t)(t_) * 32 + laneOff, dst_ + r0_ * 32); \
} while (0)

#define SB0()  __builtin_amdgcn_sched_barrier(0)
#define BAR()  asm volatile("s_barrier" ::: "memory")
#define VM0()  asm volatile("s_waitcnt vmcnt(0)" ::: "memory")

// one K-tile: X = current buf, Y = next (cross-reads), Z = stage target (t+2)
#define KT(XA_, XB_, YA_, YB_, ZA_, ZB_, t_) do { \
  const bool st_ = (t_) + 2 < NT, cr_ = (t_) + 1 < NT; \
  if (grpE) { \
    /* E1 (0,0) */ \
    RB32(bQ, XB_, 1); \
    if (st_) { STG32(ZA_, Ab, (t_) + 2, 0); STG32(ZA_, Ab, (t_) + 2, 1); } \
    SB0(); MFMA8(0, 0, aP, bP); SB0(); \
    /* E2 (0,1) */ \
    RA32(aQ, XA_, 1); \
    if (st_) { STG32(ZB_, Bb, (t_) + 2, 0); STG32(ZB_, Bb, (t_) + 2, 1); } \
    SB0(); MFMA8(0, 1, aP, bQ); SB0(); \
    /* E3 (1,1) | cross-read next tile's A(0) (aP dead after E2) */ \
    if (cr_) RA32(aP, YA_, 0); \
    SB0(); MFMA8(1, 1, aQ, bQ); SB0(); \
    /* E4 (1,0) | cross-read next tile's B(0) AFTER bP's last use */ \
    MFMA8(1, 0, aQ, bP); SB0(); \
    if (cr_) RB32(bP, YB_, 0); \
    SB0(); \
  } else { \
    /* O1 (1,1) */ \
    RB32(bQ, XB_, 0); \
    if (st_) { STG32(ZA_, Ab, (t_) + 2, 0); STG32(ZA_, Ab, (t_) + 2, 1); } \
    SB0(); MFMA8(1, 1, aP, bP); SB0(); \
    /* O2 (1,0) */ \
    RA32(aQ, XA_, 0); \
    if (st_) { STG32(ZB_, Bb, (t_) + 2, 0); STG32(ZB_, Bb, (t_) + 2, 1); } \
    SB0(); MFMA8(1, 0, aP, bQ); SB0(); \
    /* O3 (0,0) | cross-read next tile's A(1) (aP dead after O2) */ \
    if (cr_) RA32(aP, YA_, 1); \
    SB0(); MFMA8(0, 0, aQ, bQ); SB0(); \
    /* O4 (0,1) | cross-read next tile's B(1) AFTER bP's last use */ \
    MFMA8(0, 1, aQ, bP); SB0(); \
    if (cr_) RB32(bP, YB_, 1); \
    SB0(); \
  } \
  VM0(); BAR(); \
} while (0)

template <bool OUT_BF16>
__launch_bounds__(512)
__global__ void gemm_8ph(const ushort_t* __restrict__ A,   // [M,K] bf16
                         const ushort_t* __restrict__ Bt,  // [N,K] bf16
                         void* __restrict__ Cv, int M, int N, int K) {
  extern __shared__ __attribute__((aligned(128))) ushort_t smem[];
  const int tid = threadIdx.x, lane = tid & 63, w = tid >> 6;   // w 0..7
  const int wm = (w >> 2) * 128, wn = (w & 3) * 64;
  const int l15 = lane & 15, lq = lane >> 4;
  const bool grpE = (w < 4);   // SIMD pairs (w, w+4): one E-wave + one O-wave

  // T1: XCD-aware swizzle of the linear block id (grid %8 == 0)
  const int nwg  = gridDim.x * gridDim.y;
  const int orig = blockIdx.y * gridDim.x + blockIdx.x;
  const int cpx  = nwg >> 3;
  const int swz  = (orig & 7) * cpx + (orig >> 3);
  const int bx   = swz % gridDim.x, by = swz / gridDim.x;
  const int bm = by * 256, bn = bx * 256;
  const int NT = K >> 5;   // K=2304 -> 72, divisible by 3

  const ushort_t* Ab = A + (size_t)bm * K;
  const ushort_t* Bb = Bt + (size_t)bn * K;
  // per-lane source offset: row += lane>>2, chunk = (lane&3)^((lane>>2)&3)
  const size_t laneOff = (size_t)(lane >> 2) * K + (size_t)((((lane & 3) ^ ((lane >> 2) & 3))) * 8);

  // 6 regions of 256x32 bf16 (16 KB each): A0,A1,A2,B0,B1,B2
  ushort_t* A0_ = smem;
  ushort_t* A1_ = smem + 8192;
  ushort_t* A2_ = smem + 16384;
  ushort_t* B0_ = smem + 24576;
  ushort_t* B1_ = smem + 32768;
  ushort_t* B2_ = smem + 40960;

  floatx4 acc[8][4] = {};
  bf16x8 aP[4], aQ[4], bP[2], bQ[2];

  // ---- prologue: stage tile0 -> buf0, tile1 -> buf1; drain; first operands
  STG32(A0_, Ab, 0, 0); STG32(A0_, Ab, 0, 1);
  STG32(B0_, Bb, 0, 0); STG32(B0_, Bb, 0, 1);
  if (NT > 1) {
    STG32(A1_, Ab, 1, 0); STG32(A1_, Ab, 1, 1);
    STG32(B1_, Bb, 1, 0); STG32(B1_, Bb, 1, 1);
  }
  VM0(); BAR();
  if (grpE) { RA32(aP, A0_, 0); RB32(bP, B0_, 0); }
  else      { RA32(aP, A0_, 1); RB32(bP, B0_, 1); }

  for (int t = 0; t < NT; t += 3) {
    KT(A0_, B0_, A1_, B1_, A2_, B2_, t);
    KT(A1_, B1_, A2_, B2_, A0_, B0_, t + 1);
    KT(A2_, B2_, A0_, B0_, A1_, B1_, t + 2);
  }

  // ---- epilogue: C write (C/D layout: row = lq*4+rr, col = l15 per 16x16 frag)
  const int r0 = lq * 4;
#pragma unroll
  for (int mf = 0; mf < 8; ++mf)
#pragma unroll
    for (int nf = 0; nf < 4; ++nf) {
      const long long base = (long long)(bm + wm + mf * 16 + r0) * N + bn + wn + nf * 16 + l15;
      if (OUT_BF16) {
        ushort_t* Cp = (ushort_t*)Cv + base;
#pragma unroll
        for (int rr = 0; rr < 4; ++rr) Cp[(long long)rr * N] = f2bf(acc[mf][nf][rr]);
      } else {
        float* Cp = (float*)Cv + base;
#pragma unroll
        for (int rr = 0; rr < 4; ++rr) Cp[(long long)rr * N] = acc[mf][nf][rr];
      }
    }
}

#undef RA32
#undef RB32
#undef MFMA8
#undef STG32
#undef SB0
#undef BAR
#undef VM0
#undef KT

// ---------------------------------------------------------------------------
// 128x128 GEMM (register-double-buffered) — output projection (576 blocks
// saturate all CUs) and fallback.
// ---------------------------------------------------------------------------
template <bool OUT_BF16>
__launch_bounds__(256)
__global__ void gemm_bt(const ushort_t* __restrict__ A,   // [M,K] bf16
                        const ushort_t* __restrict__ Bt,  // [N,K] bf16
                        void* __restrict__ Cv, int M, int N, int K) {
  __shared__ ushort_t As[128 * 64];
  __shared__ ushort_t Bs[128 * 64];
  const int tid = threadIdx.x, lane = tid & 63, wid = tid >> 6;
  const int bm = blockIdx.y * 128, bn = blockIdx.x * 128;
  const int wm = (wid >> 1) * 64, wn = (wid & 1) * 64;

  floatx4 acc[4][4] = {};

  const int r  = tid >> 1;
  const int cp = (tid & 1) * 4;
  const int wkey = r & 7;
  const ushort_t* Ap = A  + (long long)(bm + r) * K + cp * 8;
  const ushort_t* Bp = Bt + (long long)(bn + r) * K + cp * 8;
  ushort_t* Aw = &As[r * 64];
  ushort_t* Bw = &Bs[r * 64];

  const int l15 = lane & 15, lq = lane >> 4;
  const int rkey = l15 & 7;

  bf16x8 ar[4], br[4];
#pragma unroll
  for (int i = 0; i < 4; ++i) {
    ar[i] = *(const bf16x8*)(Ap + i * 8);
    br[i] = *(const bf16x8*)(Bp + i * 8);
  }

  for (int k0 = 0; k0 < K; k0 += 64) {
    __syncthreads();
#pragma unroll
    for (int i = 0; i < 4; ++i) {
      *(bf16x8*)&Aw[((cp + i) ^ wkey) * 8] = ar[i];
      *(bf16x8*)&Bw[((cp + i) ^ wkey) * 8] = br[i];
    }
    __syncthreads();

    if (k0 + 64 < K) {
      const int kn = k0 + 64;
#pragma unroll
      for (int i = 0; i < 4; ++i) {
        ar[i] = *(const bf16x8*)(Ap + kn + i * 8);
        br[i] = *(const bf16x8*)(Bp + kn + i * 8);
      }
    }

#pragma unroll
    for (int kk = 0; kk < 2; ++kk) {
      bf16x8 af[4], bfr[4];
#pragma unroll
      for (int i = 0; i < 4; ++i) {
        af[i]  = *(const bf16x8*)&As[(wm + i * 16 + l15) * 64 + ((kk * 4 + lq) ^ rkey) * 8];
        bfr[i] = *(const bf16x8*)&Bs[(wn + i * 16 + l15) * 64 + ((kk * 4 + lq) ^ rkey) * 8];
      }
#pragma unroll
      for (int i = 0; i < 4; ++i)
#pragma unroll
        for (int j = 0; j < 4; ++j)
          acc[i][j] = __builtin_amdgcn_mfma_f32_16x16x32_bf16(af[i], bfr[j], acc[i][j], 0, 0, 0);
    }
  }

  const int r0 = lq * 4, c0 = l15;
#pragma unroll
  for (int i = 0; i < 4; ++i)
#pragma unroll
    for (int j = 0; j < 4; ++j) {
      const long long base = (long long)(bm + wm + i * 16 + r0) * N + bn + wn + j * 16 + c0;
      if (OUT_BF16) {
        ushort_t* Cp = (ushort_t*)Cv + base;
#pragma unroll
        for (int rr = 0; rr < 4; ++rr) Cp[(long long)rr * N] = f2bf(acc[i][j][rr]);
      } else {
        float* Cp = (float*)Cv + base;
#pragma unroll
        for (int rr = 0; rr < 4; ++rr) Cp[(long long)rr * N] = acc[i][j][rr];
      }
    }
}

// ---------------------------------------------------------------------------
// In-place RoPE on QKV16 [B*S][4096] bf16 (Q cols 0..2047, K cols 2048..3071).
// Also folds the 1/16 attention scale into Q. V region untouched.
// ---------------------------------------------------------------------------
__global__ void rope_inplace(ushort_t* __restrict__ QKV16, const int* __restrict__ pos) {
  const int bs  = blockIdx.x;
  const int gid = blockIdx.y * 256 + threadIdx.x;
  const int head = gid >> 7;          // 0..11
  const int d    = gid & 127;
  const float pp   = (float)pos[bs];
  const float invf = __expf(-(float)d * (9.210340371976184f / 128.0f));
  const float ang  = pp * invf;
  float sn, cc;
  __sincosf(ang, &sn, &cc);
  ushort_t* base = QKV16 + (size_t)bs * QKVW + head * HD_;
  const float x1 = bf2f(base[d]);
  const float x2 = bf2f(base[d + 128]);
  float o1 = x1 * cc - x2 * sn;
  float o2 = x2 * cc + x1 * sn;
  if (head < NH_) { o1 *= 0.0625f; o2 *= 0.0625f; }   // fold 1/sqrt(256) into Q
  base[d]       = f2bf(o1);
  base[d + 128] = f2bf(o2);
}

// ---------------------------------------------------------------------------
// V transpose: QKV16 V region -> Vt16 [B][NKV][256][S] bf16.
// ---------------------------------------------------------------------------
__global__ void v_prep(const ushort_t* __restrict__ QKV16, ushort_t* __restrict__ Vt16) {
  __shared__ ushort_t tile[32][33];
  const int k0 = blockIdx.x * 32, d0 = blockIdx.y * 32;
  const int b = blockIdx.z >> 2, hk = blockIdx.z & 3;
  const int lx = threadIdx.x & 31, ly = threadIdx.x >> 5;
#pragma unroll
  for (int i = 0; i < 4; ++i)
    tile[ly + 8 * i][lx] =
        QKV16[(size_t)(b * S_ + k0 + ly + 8 * i) * QKVW + 3072 + hk * HD_ + d0 + lx];
  __syncthreads();
#pragma unroll
  for (int i = 0; i < 4; ++i)
    Vt16[((size_t)(b * NKV_ + hk) * HD_ + d0 + ly + 8 * i) * S_ + k0 + lx] =
        tile[lx][ly + 8 * i];
}

// ---------------------------------------------------------------------------
// MFMA flash attention, head-PAIR per block (both heads share hk's K/V).
// 512 threads = 8 waves: waves 0-3 -> head 2*hp, waves 4-7 -> head 2*hp+1.
// ---------------------------------------------------------------------------
__launch_bounds__(512)
__global__ void attn_mfma(const ushort_t* __restrict__ QKV16,  // [B*S][4096]
                          const ushort_t* __restrict__ Vt16,   // [B][NKV][256][S]
                          ushort_t* __restrict__ AOb) {        // [B][S][NH][256]
  __shared__ ushort_t Ks[32 * 256];    // [key][dim], chunk-swizzled
  __shared__ ushort_t Vts[256 * 32];   // [dim][key], chunk-swizzled
  __shared__ ushort_t Ps[8][16 * 32];  // per-wave P [q][key], chunk-swizzled
  __shared__ float rsb[8][16];

  const int lane = threadIdx.x & 63, w = threadIdx.x >> 6;   // w 0..7
  const int l15 = lane & 15, lq = lane >> 4;
  const int qb = blockIdx.x * 64;
  const int hp = blockIdx.y, b = blockIdx.z;                 // hp = hk
  const int h  = hp * 2 + (w >> 2);
  const int hw = w & 3;                                      // wave-in-head

  const ushort_t* Qh = QKV16 + (size_t)b * S_ * QKVW + h * HD_;
  const ushort_t* Kh = QKV16 + (size_t)b * S_ * QKVW + 2048 + hp * HD_;
  const ushort_t* Vh = Vt16 + ((size_t)(b * NKV_ + hp) * HD_) * S_;

  const int qw = qb + hw * 16;   // wave's first query

  bf16x8 afq[8];
  {
    const ushort_t* qr = Qh + (size_t)(qw + l15) * QKVW + lq * 8;
#pragma unroll
    for (int kd = 0; kd < 8; ++kd) afq[kd] = *(const bf16x8*)(qr + kd * 32);
  }

  floatx4 acc[16] = {};
  float rs[4] = {0.f, 0.f, 0.f, 0.f};

  int kb0 = qb - (WIN_ - 1);
  if (kb0 < 0) kb0 = 0;
  kb0 &= ~31;

  const int ksp = lane & 31, ksr = lane >> 5;
  const int vsp = lane & 3,  vsr = lane >> 2;

  for (int kb = kb0; kb < qb + 64; kb += 32) {
    __syncthreads();
#pragma unroll
    for (int i = 0; i < 2; ++i) {
      const int kl = w * 4 + 2 * i + ksr;
      gl2lds16(Kh + (size_t)(kb + kl) * QKVW + (ksp ^ (kl & 31)) * 8,
               &Ks[(w * 4 + 2 * i) * 256]);
    }
#pragma unroll
    for (int i = 0; i < 2; ++i) {
      const int dl = w * 32 + 16 * i + vsr;
      gl2lds16(Vh + (size_t)dl * S_ + kb + (vsp ^ ((dl >> 1) & 3)) * 8,
               &Vts[(w * 32 + 16 * i) * 32]);
    }
    __syncthreads();

    if (kb <= qw + 15 && kb + 31 >= qw - (WIN_ - 1)) {
      ushort_t* Pw = Ps[w];
#pragma unroll
      for (int kt = 0; kt < 2; ++kt) {
        floatx4 sacc = {};
        const int keyl = kt * 16 + l15;
        const int krow = keyl * 256;
        const int ksw = keyl & 31;
#pragma unroll
        for (int kd = 0; kd < 8; ++kd) {
          bf16x8 bk = *(const bf16x8*)&Ks[krow + ((kd * 4 + lq) ^ ksw) * 8];
          sacc = __builtin_amdgcn_mfma_f32_16x16x32_bf16(afq[kd], bk, sacc, 0, 0, 0);
        }
        const int keyg = kb + keyl;
#pragma unroll
        for (int rr = 0; rr < 4; ++rr) {
          const int qg = qw + lq * 4 + rr;
          const float t = __expf(sacc[rr] * 0.04f);
          const float L = 50.f - __fdividef(100.f, t + 1.f);
          float p = __expf(L);
          p = (keyg <= qg && keyg >= qg - (WIN_ - 1)) ? p : 0.f;
          rs[rr] += p;
          const int ql = lq * 4 + rr;
          const int ch = kt * 2 + (l15 >> 3);
          Pw[ql * 32 + ((ch ^ ((ql >> 1) & 3)) * 8) + (l15 & 7)] = f2bf(p);
        }
      }
      asm volatile("s_waitcnt lgkmcnt(0)" ::: "memory");

      const bf16x8 bp = *(const bf16x8*)&Pw[l15 * 32 + ((lq ^ ((l15 >> 1) & 3)) * 8)];
      const int vsw = (l15 >> 1) & 3;
#pragma unroll
      for (int t = 0; t < 16; ++t) {
        bf16x8 av = *(const bf16x8*)&Vts[(t * 16 + l15) * 32 + ((lq ^ vsw) * 8)];
        acc[t] = __builtin_amdgcn_mfma_f32_16x16x32_bf16(av, bp, acc[t], 0, 0, 0);
      }
    }
  }

#pragma unroll
  for (int rr = 0; rr < 4; ++rr) {
    rs[rr] += __shfl_xor(rs[rr], 1, 64);
    rs[rr] += __shfl_xor(rs[rr], 2, 64);
    rs[rr] += __shfl_xor(rs[rr], 4, 64);
    rs[rr] += __shfl_xor(rs[rr], 8, 64);
  }
  if (l15 == 0) {
#pragma unroll
    for (int rr = 0; rr < 4; ++rr) rsb[w][lq * 4 + rr] = rs[rr];
  }
  asm volatile("s_waitcnt lgkmcnt(0)" ::: "memory");
  __builtin_amdgcn_wave_barrier();
  const float inv = 1.0f / rsb[w][l15];

  const size_t ob = ((size_t)(b * S_ + qw + l15) * NH_ + h) * HD_;
#pragma unroll
  for (int t = 0; t < 16; ++t) {
    ushort4 o;
    o.x = f2bf(acc[t][0] * inv);
    o.y = f2bf(acc[t][1] * inv);
    o.z = f2bf(acc[t][2] * inv);
    o.w = f2bf(acc[t][3] * inv);
    *(ushort4*)&AOb[ob + t * 16 + lq * 4] = o;
  }
}

// ---------------------------------------------------------------------------
extern "C" void kernel_launch(void* const* d_in, const int* in_sizes, int n_in,
                              void* d_out, int out_size, void* d_ws, size_t ws_size,
                              hipStream_t stream) {
  const float* X   = (const float*)d_in[0];
  const int*   pos = (const int*)d_in[2];
  const float* Wq  = (const float*)d_in[3];   // [2304, 2048]
  const float* Wk  = (const float*)d_in[4];   // [2304, 1024]
  const float* Wv  = (const float*)d_in[5];   // [2304, 1024]
  const float* Wo  = (const float*)d_in[6];   // [2048, 2304]
  float* out = (float*)d_out;

  const int M  = B_ * S_;        // 4096
  const int NQ = NH_ * HD_;      // 2048
  const int NK = NKV_ * HD_;     // 1024

  char* w = (char*)d_ws;
  ushort_t* QKV16 = (ushort_t*)w;  w += (size_t)M * QKVW * 2;          // 32 MB
  ushort_t* Xb    = (ushort_t*)w;  w += (size_t)M * H_ * 2;            // 18 MB
  ushort_t* Wqkvt = (ushort_t*)w;  w += (size_t)QKVW * H_ * 2;         // 18 MB
  ushort_t* Wot   = (ushort_t*)w;  w += (size_t)H_ * NQ * 2;           // 9.4 MB
  ushort_t* Vt16  = (ushort_t*)w;  w += (size_t)B_ * NKV_ * S_ * HD_ * 2;  // 8 MB
  ushort_t* AOb   = (ushort_t*)w;  w += (size_t)M * NQ * 2;            // 16 MB

  // opt-in to 96 KiB dynamic LDS for the tri-buffered GEMM (host-side, capture-safe)
  static bool g_init = false, g_8ph_ok = false;
  if (!g_init) {
    hipError_t e1 = hipFuncSetAttribute(
        reinterpret_cast<const void*>(&gemm_8ph<true>),
        hipFuncAttributeMaxDynamicSharedMemorySize, 98304);
    g_8ph_ok = (e1 == hipSuccess);
    g_init = true;
  }

  dim3 blk(256);

  cast_bf16<<<(M * H_) / 1024, blk, 0, stream>>>(X, Xb);
  // concatenated transposed QKV weights: rows [0,2048)=Wq^T, [2048,3072)=Wk^T, [3072,4096)=Wv^T
  transpose_cast<<<dim3(NQ / 32, H_ / 32), blk, 0, stream>>>(Wq, Wqkvt, H_, NQ);
  transpose_cast<<<dim3(NK / 32, H_ / 32), blk, 0, stream>>>(Wk, Wqkvt + (size_t)2048 * H_, H_, NK);
  transpose_cast<<<dim3(NK / 32, H_ / 32), blk, 0, stream>>>(Wv, Wqkvt + (size_t)3072 * H_, H_, NK);
  transpose_cast<<<dim3(H_ / 32, NQ / 32), blk, 0, stream>>>(Wo, Wot, NQ, H_);

  // fused QKV projection, bf16 out (K=2304 -> NT=72, %3==0; grid 16x16=256)
  if (g_8ph_ok) {
    gemm_8ph<true><<<dim3(QKVW / 256, M / 256), dim3(512), 98304, stream>>>(
        Xb, Wqkvt, QKV16, M, QKVW, H_);
  } else {
    gemm_bt<true><<<dim3(QKVW / 128, M / 128), blk, 0, stream>>>(Xb, Wqkvt, QKV16, M, QKVW, H_);
  }

  rope_inplace<<<dim3(M, 6), blk, 0, stream>>>(QKV16, pos);
  v_prep<<<dim3(S_ / 32, HD_ / 32, B_ * NKV_), blk, 0, stream>>>(QKV16, Vt16);

  // attention: head-pair per block, 512 threads
  attn_mfma<<<dim3(S_ / 64, NKV_, B_), dim3(512), 0, stream>>>(QKV16, Vt16, AOb);

  // output projection, fp32 out: 128^2 tiles -> 576 blocks (saturates 256 CUs)
  gemm_bt<false><<<dim3(H_ / 128, M / 128), blk, 0, stream>>>(AOb, Wot, out, M, H_, NQ);
}

// Round 6
// 361.041 us; speedup vs baseline: 1.9782x; 1.9782x over previous
//
#include <hip/hip_runtime.h>
#include <cmath>

#define B_   2
#define S_   2048
#define H_   2304
#define NH_  8
#define HD_  256
#define NKV_ 4
#define WIN_ 512
#define QKVW 4096   // fused QKV output row width (8+4+4 heads * 256)

typedef unsigned short ushort_t;
typedef __attribute__((ext_vector_type(8))) short bf16x8;     // 8 bf16 = 4 VGPRs
typedef __attribute__((ext_vector_type(4))) float floatx4;

// round-to-nearest-even fp32 -> bf16
__device__ __forceinline__ unsigned short f2bf(float f) {
  unsigned u = __builtin_bit_cast(unsigned, f);
  u += 0x7fff + ((u >> 16) & 1);
  return (unsigned short)(u >> 16);
}
__device__ __forceinline__ float bf2f(ushort_t v) {
  unsigned u = (unsigned)v << 16;
  return __builtin_bit_cast(float, u);
}

// async global->LDS, 16 B per lane. LDS dest = wave-uniform base + lane*16.
__device__ __forceinline__ void gl2lds16(const void* g, void* l) {
  __builtin_amdgcn_global_load_lds(
      (const __attribute__((address_space(1))) unsigned int*)g,
      (__attribute__((address_space(3))) unsigned int*)l, 16, 0, 0);
}

// ---------------------------------------------------------------------------
// Elementwise fp32 -> bf16 cast (4 elems/thread).
// ---------------------------------------------------------------------------
__global__ void cast_bf16(const float* __restrict__ in, ushort_t* __restrict__ out) {
  const int i = blockIdx.x * 256 + threadIdx.x;
  float4 v = ((const float4*)in)[i];
  ushort4 o;
  o.x = f2bf(v.x); o.y = f2bf(v.y); o.z = f2bf(v.z); o.w = f2bf(v.w);
  ((ushort4*)out)[i] = o;
}

// ---------------------------------------------------------------------------
// W[K,N] fp32 -> Wt[N,K] bf16 (32x32 LDS tiles, 256 threads).
// ---------------------------------------------------------------------------
__global__ void transpose_cast(const float* __restrict__ W, ushort_t* __restrict__ Wt,
                               int K, int N) {
  __shared__ float t[32][33];
  const int lx = threadIdx.x & 31, ly = threadIdx.x >> 5;   // ly 0..7
  const int n0 = blockIdx.x * 32, k0 = blockIdx.y * 32;
#pragma unroll
  for (int i = 0; i < 4; ++i)
    t[ly + i * 8][lx] = W[(long long)(k0 + ly + i * 8) * N + n0 + lx];
  __syncthreads();
#pragma unroll
  for (int i = 0; i < 4; ++i)
    Wt[(long long)(n0 + ly + i * 8) * K + k0 + lx] = f2bf(t[lx][ly + i * 8]);
}

// ===========================================================================
// 256x256-tile bf16 MFMA GEMM, v6: FAITHFUL m201 8-phase skeleton.
//   C[M,N] = A[M,K] @ Bt[N,K]^T     (NT = K/64 must be EVEN: 36 / 32)
// 512 threads = 8 waves (2M x 4N), per-wave 128x64 (acc[8][4]), BK=64,
// 128 KiB dynamic LDS double buffer (buf0=even tiles, buf1=odd),
// global_load_lds width=16, chunk^(row&7) swizzle via pre-swizzled GLOBAL
// source (linear LDS dest, 0 bank conflicts — r0-r4 verified).
//
// PER PHASE (the template, not a variant):
//   { ds-read THIS phase's quadrant operands (12/4/8/4 gray-code) |
//     stage 1 half-tile (2 gl2lds/wave) | [lgkmcnt(8) if 12 reads] |
//     BARRIER | lgkmcnt(0)+sched_barrier | setprio(1) 16 MFMA setprio(0) |
//     [vmcnt at ph4/ph8] | BARRIER }
// 8 phases / 2 K-tiles; quadrants (0,0)(0,1)(1,1)(1,0) per tile.
// Reads-before-own-MFMA + double barrier de-phases waves: all 8 waves'
// reads hit the LDS queue before any MFMA; first-served wave starts its
// MFMA cluster while LDS drains the rest (r1/r2/r4 all kept waves in
// lockstep, alternating pipes -> 40% MfmaUtil plateau).
//
// Stage map (region freed >=1 barrier before its stage issues; checked):
//   ph1 A1(t+1)  ph2 B0(t+1)  ph3 A0(t+2)  ph4 B1(t+2)
//   ph5 A1(t+2)  ph6 B0(t+2)  ph7 A0(t+3)  ph8 B1(t+3)
// vmcnt(4) at ph4: outstanding 12 {prev ph7,ph8; ph1..ph4} -> drains 8
// oldest = tile t+1 complete (needed ph5-8). vmcnt(4) at ph8: drains
// through ph6 = tile t+2 complete (needed next ph1-4). Last iter: vmcnt(0).
// Prologue stages tile0 (8) + A0,B1 of tile1 (4) = the steady-state
// "prev ph7/ph8" pair; vmcnt(4) leaves exactly those in flight.
// ===========================================================================
#define RA(base_, qm_) do { \
  _Pragma("unroll") for (int i_ = 0; i_ < 4; ++i_) { \
    const int row_ = wm + (qm_) * 64 + i_ * 16 + l15; \
    _Pragma("unroll") for (int kk_ = 0; kk_ < 2; ++kk_) \
      a[i_][kk_] = *(const bf16x8*)&(base_)[row_ * 64 + (((kk_ * 4 + lq) ^ (l15 & 7)) * 8)]; \
  } \
} while (0)

#define RB(base_, qn_) do { \
  _Pragma("unroll") for (int j_ = 0; j_ < 2; ++j_) { \
    const int row_ = wn + (qn_) * 32 + j_ * 16 + l15; \
    _Pragma("unroll") for (int kk_ = 0; kk_ < 2; ++kk_) \
      b[j_][kk_] = *(const bf16x8*)&(base_)[row_ * 64 + (((kk_ * 4 + lq) ^ (l15 & 7)) * 8)]; \
  } \
} while (0)

#define MFMAQ(qm_, qn_) do { \
  __builtin_amdgcn_s_setprio(1); \
  _Pragma("unroll") for (int kk_ = 0; kk_ < 2; ++kk_) \
  _Pragma("unroll") for (int i_ = 0; i_ < 4; ++i_) \
  _Pragma("unroll") for (int j_ = 0; j_ < 2; ++j_) \
    acc[(qm_) * 4 + i_][(qn_) * 2 + j_] = __builtin_amdgcn_mfma_f32_16x16x32_bf16( \
        a[i_][kk_], b[j_][kk_], acc[(qm_) * 4 + i_][(qn_) * 2 + j_], 0, 0, 0); \
  __builtin_amdgcn_s_setprio(0); \
} while (0)

// stage one 128-row x 64-col half-tile (16 KB): 2 x global_load_lds per lane.
// A-half qm: rows {qm*64..+63} U {128+qm*64..+63} (quadrant (qm,.) rows of
// both wave groups). B-half qn: rows {q*64+qn*32..+31} for q=0..3.
#define STAGE_A(dst_, gsrc_, t_, qm_) do { \
  _Pragma("unroll") for (int jj_ = 0; jj_ < 2; ++jj_) { \
    const int g_ = w * 2 + jj_; \
    const int tr0_ = ((g_ >> 3) * 128) + (qm_) * 64 + (g_ & 7) * 8; \
    gl2lds16(gsrc_ + (size_t)tr0_ * K + (size_t)(t_) * 64 + laneOff, dst_ + tr0_ * 64); \
  } \
} while (0)

#define STAGE_B(dst_, gsrc_, t_, qn_) do { \
  _Pragma("unroll") for (int jj_ = 0; jj_ < 2; ++jj_) { \
    const int g_ = w * 2 + jj_; \
    const int tr0_ = ((g_ >> 2) * 64) + (qn_) * 32 + (g_ & 3) * 8; \
    gl2lds16(gsrc_ + (size_t)tr0_ * K + (size_t)(t_) * 64 + laneOff, dst_ + tr0_ * 64); \
  } \
} while (0)

#define SB0()   __builtin_amdgcn_sched_barrier(0)
#define BARR()  do { SB0(); __builtin_amdgcn_s_barrier(); } while (0)
#define LGKM0() do { asm volatile("s_waitcnt lgkmcnt(0)" ::: "memory"); SB0(); } while (0)
#define LGKM8() asm volatile("s_waitcnt lgkmcnt(8)" ::: "memory")
#define VM(n_)  asm volatile("s_waitcnt vmcnt(" #n_ ")" ::: "memory")

template <bool OUT_BF16>
__launch_bounds__(512)
__global__ void gemm_8ph(const ushort_t* __restrict__ A,   // [M,K] bf16
                         const ushort_t* __restrict__ Bt,  // [N,K] bf16
                         void* __restrict__ Cv, int M, int N, int K) {
  extern __shared__ __attribute__((aligned(128))) ushort_t smem[];
  const int tid = threadIdx.x, lane = tid & 63, w = tid >> 6;   // w 0..7
  const int wm = (w >> 2) * 128, wn = (w & 3) * 64;
  const int l15 = lane & 15, lq = lane >> 4;

  // T1: XCD-aware swizzle of the linear block id (grid %8 == 0)
  const int nwg  = gridDim.x * gridDim.y;
  const int orig = blockIdx.y * gridDim.x + blockIdx.x;
  const int cpx  = nwg >> 3;
  const int swz  = (orig & 7) * cpx + (orig >> 3);
  const int bx   = swz % gridDim.x, by = swz / gridDim.x;
  const int bm = by * 256, bn = bx * 256;
  const int NT = K >> 6;   // 36 (QKV) / 32 (out-proj) — both even

  const ushort_t* Ab = A + (size_t)bm * K;
  const ushort_t* Bb = Bt + (size_t)bn * K;
  // per-lane source offset: row += lane>>3, chunk = (lane&7)^(lane>>3) (swizzle)
  const size_t laneOff = (size_t)(lane >> 3) * K + (size_t)(((lane & 7) ^ (lane >> 3)) * 8);

  ushort_t* Ae = smem;              // even-tile A (256x64)
  ushort_t* Ao = smem + 16384;      // odd-tile  A
  ushort_t* Be = smem + 32768;      // even-tile B
  ushort_t* Bo = smem + 49152;      // odd-tile  B

  floatx4 acc[8][4] = {};
  bf16x8 a[4][2], b[2][2];

  // ---- prologue: tile0 full (8 loads) + tile1 {A0, B1} (4 loads) — the
  // steady-state "prev ph7/ph8" pair; vmcnt(4) drains tile0 exactly.
  STAGE_A(Ae, Ab, 0, 0);
  STAGE_B(Be, Bb, 0, 1);
  STAGE_A(Ae, Ab, 0, 1);
  STAGE_B(Be, Bb, 0, 0);
  STAGE_A(Ao, Ab, 1, 0);
  STAGE_B(Bo, Bb, 1, 1);
  VM(4);
  BARR();

  for (int t = 0; t < NT; t += 2) {
    const bool more = (t + 2 < NT);

    // ---- PH1: (t, q00) | stage A1(t+1)
    RA(Ae, 0); RB(Be, 0);
    STAGE_A(Ao, Ab, t + 1, 1);
    LGKM8();
    BARR();
    LGKM0();
    MFMAQ(0, 0);
    BARR();

    // ---- PH2: (t, q01) | stage B0(t+1)
    RB(Be, 1);
    STAGE_B(Bo, Bb, t + 1, 0);
    BARR();
    LGKM0();
    MFMAQ(0, 1);
    BARR();

    // ---- PH3: (t, q11) | stage A0(t+2)
    RA(Ae, 1);
    if (more) STAGE_A(Ae, Ab, t + 2, 0);
    BARR();
    LGKM0();
    MFMAQ(1, 1);
    BARR();

    // ---- PH4: (t, q10) | stage B1(t+2) | vmcnt: tile t+1 complete
    RB(Be, 0);
    if (more) STAGE_B(Be, Bb, t + 2, 1);
    BARR();
    LGKM0();
    MFMAQ(1, 0);
    SB0();
    if (more) { VM(4); } else { VM(0); }
    BARR();

    // ---- PH5: (t+1, q00) | stage A1(t+2)
    RA(Ao, 0); RB(Bo, 0);
    if (more) STAGE_A(Ae, Ab, t + 2, 1);
    LGKM8();
    BARR();
    LGKM0();
    MFMAQ(0, 0);
    BARR();

    // ---- PH6: (t+1, q01) | stage B0(t+2)
    RB(Bo, 1);
    if (more) STAGE_B(Be, Bb, t + 2, 0);
    BARR();
    LGKM0();
    MFMAQ(0, 1);
    BARR();

    // ---- PH7: (t+1, q11) | stage A0(t+3)
    RA(Ao, 1);
    if (more) STAGE_A(Ao, Ab, t + 3, 0);
    BARR();
    LGKM0();
    MFMAQ(1, 1);
    BARR();

    // ---- PH8: (t+1, q10) | stage B1(t+3) | vmcnt: tile t+2 complete
    RB(Bo, 0);
    if (more) STAGE_B(Bo, Bb, t + 3, 1);
    BARR();
    LGKM0();
    MFMAQ(1, 0);
    SB0();
    if (more) { VM(4); } else { VM(0); }
    BARR();
  }

  // ---- epilogue: C write (C/D layout: row = lq*4+rr, col = l15 per 16x16 frag)
  const int r0 = lq * 4;
#pragma unroll
  for (int mf = 0; mf < 8; ++mf)
#pragma unroll
    for (int nf = 0; nf < 4; ++nf) {
      const long long base = (long long)(bm + wm + mf * 16 + r0) * N + bn + wn + nf * 16 + l15;
      if (OUT_BF16) {
        ushort_t* Cp = (ushort_t*)Cv + base;
#pragma unroll
        for (int rr = 0; rr < 4; ++rr) Cp[(long long)rr * N] = f2bf(acc[mf][nf][rr]);
      } else {
        float* Cp = (float*)Cv + base;
#pragma unroll
        for (int rr = 0; rr < 4; ++rr) Cp[(long long)rr * N] = acc[mf][nf][rr];
      }
    }
}

#undef RA
#undef RB
#undef MFMAQ
#undef STAGE_A
#undef STAGE_B
#undef SB0
#undef BARR
#undef LGKM0
#undef LGKM8
#undef VM

// ---------------------------------------------------------------------------
// 128x128 GEMM (register-double-buffered) — output projection (576 blocks
// saturate all CUs) and fallback.
// ---------------------------------------------------------------------------
template <bool OUT_BF16>
__launch_bounds__(256)
__global__ void gemm_bt(const ushort_t* __restrict__ A,   // [M,K] bf16
                        const ushort_t* __restrict__ Bt,  // [N,K] bf16
                        void* __restrict__ Cv, int M, int N, int K) {
  __shared__ ushort_t As[128 * 64];
  __shared__ ushort_t Bs[128 * 64];
  const int tid = threadIdx.x, lane = tid & 63, wid = tid >> 6;
  const int bm = blockIdx.y * 128, bn = blockIdx.x * 128;
  const int wm = (wid >> 1) * 64, wn = (wid & 1) * 64;

  floatx4 acc[4][4] = {};

  const int r  = tid >> 1;
  const int cp = (tid & 1) * 4;
  const int wkey = r & 7;
  const ushort_t* Ap = A  + (long long)(bm + r) * K + cp * 8;
  const ushort_t* Bp = Bt + (long long)(bn + r) * K + cp * 8;
  ushort_t* Aw = &As[r * 64];
  ushort_t* Bw = &Bs[r * 64];

  const int l15 = lane & 15, lq = lane >> 4;
  const int rkey = l15 & 7;

  bf16x8 ar[4], br[4];
#pragma unroll
  for (int i = 0; i < 4; ++i) {
    ar[i] = *(const bf16x8*)(Ap + i * 8);
    br[i] = *(const bf16x8*)(Bp + i * 8);
  }

  for (int k0 = 0; k0 < K; k0 += 64) {
    __syncthreads();
#pragma unroll
    for (int i = 0; i < 4; ++i) {
      *(bf16x8*)&Aw[((cp + i) ^ wkey) * 8] = ar[i];
      *(bf16x8*)&Bw[((cp + i) ^ wkey) * 8] = br[i];
    }
    __syncthreads();

    if (k0 + 64 < K) {
      const int kn = k0 + 64;
#pragma unroll
      for (int i = 0; i < 4; ++i) {
        ar[i] = *(const bf16x8*)(Ap + kn + i * 8);
        br[i] = *(const bf16x8*)(Bp + kn + i * 8);
      }
    }

#pragma unroll
    for (int kk = 0; kk < 2; ++kk) {
      bf16x8 af[4], bfr[4];
#pragma unroll
      for (int i = 0; i < 4; ++i) {
        af[i]  = *(const bf16x8*)&As[(wm + i * 16 + l15) * 64 + ((kk * 4 + lq) ^ rkey) * 8];
        bfr[i] = *(const bf16x8*)&Bs[(wn + i * 16 + l15) * 64 + ((kk * 4 + lq) ^ rkey) * 8];
      }
#pragma unroll
      for (int i = 0; i < 4; ++i)
#pragma unroll
        for (int j = 0; j < 4; ++j)
          acc[i][j] = __builtin_amdgcn_mfma_f32_16x16x32_bf16(af[i], bfr[j], acc[i][j], 0, 0, 0);
    }
  }

  const int r0 = lq * 4, c0 = l15;
#pragma unroll
  for (int i = 0; i < 4; ++i)
#pragma unroll
    for (int j = 0; j < 4; ++j) {
      const long long base = (long long)(bm + wm + i * 16 + r0) * N + bn + wn + j * 16 + c0;
      if (OUT_BF16) {
        ushort_t* Cp = (ushort_t*)Cv + base;
#pragma unroll
        for (int rr = 0; rr < 4; ++rr) Cp[(long long)rr * N] = f2bf(acc[i][j][rr]);
      } else {
        float* Cp = (float*)Cv + base;
#pragma unroll
        for (int rr = 0; rr < 4; ++rr) Cp[(long long)rr * N] = acc[i][j][rr];
      }
    }
}

// ---------------------------------------------------------------------------
// In-place RoPE on QKV16 [B*S][4096] bf16 (Q cols 0..2047, K cols 2048..3071).
// Also folds the 1/16 attention scale into Q. V region untouched.
// ---------------------------------------------------------------------------
__global__ void rope_inplace(ushort_t* __restrict__ QKV16, const int* __restrict__ pos) {
  const int bs  = blockIdx.x;
  const int gid = blockIdx.y * 256 + threadIdx.x;
  const int head = gid >> 7;          // 0..11
  const int d    = gid & 127;
  const float pp   = (float)pos[bs];
  const float invf = __expf(-(float)d * (9.210340371976184f / 128.0f));
  const float ang  = pp * invf;
  float sn, cc;
  __sincosf(ang, &sn, &cc);
  ushort_t* base = QKV16 + (size_t)bs * QKVW + head * HD_;
  const float x1 = bf2f(base[d]);
  const float x2 = bf2f(base[d + 128]);
  float o1 = x1 * cc - x2 * sn;
  float o2 = x2 * cc + x1 * sn;
  if (head < NH_) { o1 *= 0.0625f; o2 *= 0.0625f; }   // fold 1/sqrt(256) into Q
  base[d]       = f2bf(o1);
  base[d + 128] = f2bf(o2);
}

// ---------------------------------------------------------------------------
// V transpose: QKV16 V region -> Vt16 [B][NKV][256][S] bf16.
// ---------------------------------------------------------------------------
__global__ void v_prep(const ushort_t* __restrict__ QKV16, ushort_t* __restrict__ Vt16) {
  __shared__ ushort_t tile[32][33];
  const int k0 = blockIdx.x * 32, d0 = blockIdx.y * 32;
  const int b = blockIdx.z >> 2, hk = blockIdx.z & 3;
  const int lx = threadIdx.x & 31, ly = threadIdx.x >> 5;
#pragma unroll
  for (int i = 0; i < 4; ++i)
    tile[ly + 8 * i][lx] =
        QKV16[(size_t)(b * S_ + k0 + ly + 8 * i) * QKVW + 3072 + hk * HD_ + d0 + lx];
  __syncthreads();
#pragma unroll
  for (int i = 0; i < 4; ++i)
    Vt16[((size_t)(b * NKV_ + hk) * HD_ + d0 + ly + 8 * i) * S_ + k0 + lx] =
        tile[lx][ly + 8 * i];
}

// ---------------------------------------------------------------------------
// MFMA flash attention, head-PAIR per block (both heads share hk's K/V).
// 512 threads = 8 waves: waves 0-3 -> head 2*hp, waves 4-7 -> head 2*hp+1.
// ---------------------------------------------------------------------------
__launch_bounds__(512)
__global__ void attn_mfma(const ushort_t* __restrict__ QKV16,  // [B*S][4096]
                          const ushort_t* __restrict__ Vt16,   // [B][NKV][256][S]
                          ushort_t* __restrict__ AOb) {        // [B][S][NH][256]
  __shared__ ushort_t Ks[32 * 256];    // [key][dim], chunk-swizzled
  __shared__ ushort_t Vts[256 * 32];   // [dim][key], chunk-swizzled
  __shared__ ushort_t Ps[8][16 * 32];  // per-wave P [q][key], chunk-swizzled
  __shared__ float rsb[8][16];

  const int lane = threadIdx.x & 63, w = threadIdx.x >> 6;   // w 0..7
  const int l15 = lane & 15, lq = lane >> 4;
  const int qb = blockIdx.x * 64;
  const int hp = blockIdx.y, b = blockIdx.z;                 // hp = hk
  const int h  = hp * 2 + (w >> 2);
  const int hw = w & 3;                                      // wave-in-head

  const ushort_t* Qh = QKV16 + (size_t)b * S_ * QKVW + h * HD_;
  const ushort_t* Kh = QKV16 + (size_t)b * S_ * QKVW + 2048 + hp * HD_;
  const ushort_t* Vh = Vt16 + ((size_t)(b * NKV_ + hp) * HD_) * S_;

  const int qw = qb + hw * 16;   // wave's first query

  bf16x8 afq[8];
  {
    const ushort_t* qr = Qh + (size_t)(qw + l15) * QKVW + lq * 8;
#pragma unroll
    for (int kd = 0; kd < 8; ++kd) afq[kd] = *(const bf16x8*)(qr + kd * 32);
  }

  floatx4 acc[16] = {};
  float rs[4] = {0.f, 0.f, 0.f, 0.f};

  int kb0 = qb - (WIN_ - 1);
  if (kb0 < 0) kb0 = 0;
  kb0 &= ~31;

  const int ksp = lane & 31, ksr = lane >> 5;
  const int vsp = lane & 3,  vsr = lane >> 2;

  for (int kb = kb0; kb < qb + 64; kb += 32) {
    __syncthreads();
#pragma unroll
    for (int i = 0; i < 2; ++i) {
      const int kl = w * 4 + 2 * i + ksr;
      gl2lds16(Kh + (size_t)(kb + kl) * QKVW + (ksp ^ (kl & 31)) * 8,
               &Ks[(w * 4 + 2 * i) * 256]);
    }
#pragma unroll
    for (int i = 0; i < 2; ++i) {
      const int dl = w * 32 + 16 * i + vsr;
      gl2lds16(Vh + (size_t)dl * S_ + kb + (vsp ^ ((dl >> 1) & 3)) * 8,
               &Vts[(w * 32 + 16 * i) * 32]);
    }
    __syncthreads();

    if (kb <= qw + 15 && kb + 31 >= qw - (WIN_ - 1)) {
      ushort_t* Pw = Ps[w];
#pragma unroll
      for (int kt = 0; kt < 2; ++kt) {
        floatx4 sacc = {};
        const int keyl = kt * 16 + l15;
        const int krow = keyl * 256;
        const int ksw = keyl & 31;
#pragma unroll
        for (int kd = 0; kd < 8; ++kd) {
          bf16x8 bk = *(const bf16x8*)&Ks[krow + ((kd * 4 + lq) ^ ksw) * 8];
          sacc = __builtin_amdgcn_mfma_f32_16x16x32_bf16(afq[kd], bk, sacc, 0, 0, 0);
        }
        const int keyg = kb + keyl;
#pragma unroll
        for (int rr = 0; rr < 4; ++rr) {
          const int qg = qw + lq * 4 + rr;
          const float t = __expf(sacc[rr] * 0.04f);
          const float L = 50.f - __fdividef(100.f, t + 1.f);
          float p = __expf(L);
          p = (keyg <= qg && keyg >= qg - (WIN_ - 1)) ? p : 0.f;
          rs[rr] += p;
          const int ql = lq * 4 + rr;
          const int ch = kt * 2 + (l15 >> 3);
          Pw[ql * 32 + ((ch ^ ((ql >> 1) & 3)) * 8) + (l15 & 7)] = f2bf(p);
        }
      }
      asm volatile("s_waitcnt lgkmcnt(0)" ::: "memory");

      const bf16x8 bp = *(const bf16x8*)&Pw[l15 * 32 + ((lq ^ ((l15 >> 1) & 3)) * 8)];
      const int vsw = (l15 >> 1) & 3;
#pragma unroll
      for (int t = 0; t < 16; ++t) {
        bf16x8 av = *(const bf16x8*)&Vts[(t * 16 + l15) * 32 + ((lq ^ vsw) * 8)];
        acc[t] = __builtin_amdgcn_mfma_f32_16x16x32_bf16(av, bp, acc[t], 0, 0, 0);
      }
    }
  }

#pragma unroll
  for (int rr = 0; rr < 4; ++rr) {
    rs[rr] += __shfl_xor(rs[rr], 1, 64);
    rs[rr] += __shfl_xor(rs[rr], 2, 64);
    rs[rr] += __shfl_xor(rs[rr], 4, 64);
    rs[rr] += __shfl_xor(rs[rr], 8, 64);
  }
  if (l15 == 0) {
#pragma unroll
    for (int rr = 0; rr < 4; ++rr) rsb[w][lq * 4 + rr] = rs[rr];
  }
  asm volatile("s_waitcnt lgkmcnt(0)" ::: "memory");
  __builtin_amdgcn_wave_barrier();
  const float inv = 1.0f / rsb[w][l15];

  const size_t ob = ((size_t)(b * S_ + qw + l15) * NH_ + h) * HD_;
#pragma unroll
  for (int t = 0; t < 16; ++t) {
    ushort4 o;
    o.x = f2bf(acc[t][0] * inv);
    o.y = f2bf(acc[t][1] * inv);
    o.z = f2bf(acc[t][2] * inv);
    o.w = f2bf(acc[t][3] * inv);
    *(ushort4*)&AOb[ob + t * 16 + lq * 4] = o;
  }
}

// ---------------------------------------------------------------------------
extern "C" void kernel_launch(void* const* d_in, const int* in_sizes, int n_in,
                              void* d_out, int out_size, void* d_ws, size_t ws_size,
                              hipStream_t stream) {
  const float* X   = (const float*)d_in[0];
  const int*   pos = (const int*)d_in[2];
  const float* Wq  = (const float*)d_in[3];   // [2304, 2048]
  const float* Wk  = (const float*)d_in[4];   // [2304, 1024]
  const float* Wv  = (const float*)d_in[5];   // [2304, 1024]
  const float* Wo  = (const float*)d_in[6];   // [2048, 2304]
  float* out = (float*)d_out;

  const int M  = B_ * S_;        // 4096
  const int NQ = NH_ * HD_;      // 2048
  const int NK = NKV_ * HD_;     // 1024

  char* w = (char*)d_ws;
  ushort_t* QKV16 = (ushort_t*)w;  w += (size_t)M * QKVW * 2;          // 32 MB
  ushort_t* Xb    = (ushort_t*)w;  w += (size_t)M * H_ * 2;            // 18 MB
  ushort_t* Wqkvt = (ushort_t*)w;  w += (size_t)QKVW * H_ * 2;         // 18 MB
  ushort_t* Wot   = (ushort_t*)w;  w += (size_t)H_ * NQ * 2;           // 9.4 MB
  ushort_t* Vt16  = (ushort_t*)w;  w += (size_t)B_ * NKV_ * S_ * HD_ * 2;  // 8 MB
  ushort_t* AOb   = (ushort_t*)w;  w += (size_t)M * NQ * 2;            // 16 MB

  // opt-in to 128 KiB dynamic LDS for the 8-phase GEMM (host-side, capture-safe)
  static bool g_init = false, g_8ph_ok = false;
  if (!g_init) {
    hipError_t e1 = hipFuncSetAttribute(
        reinterpret_cast<const void*>(&gemm_8ph<true>),
        hipFuncAttributeMaxDynamicSharedMemorySize, 131072);
    g_8ph_ok = (e1 == hipSuccess);
    g_init = true;
  }

  dim3 blk(256);

  cast_bf16<<<(M * H_) / 1024, blk, 0, stream>>>(X, Xb);
  // concatenated transposed QKV weights: rows [0,2048)=Wq^T, [2048,3072)=Wk^T, [3072,4096)=Wv^T
  transpose_cast<<<dim3(NQ / 32, H_ / 32), blk, 0, stream>>>(Wq, Wqkvt, H_, NQ);
  transpose_cast<<<dim3(NK / 32, H_ / 32), blk, 0, stream>>>(Wk, Wqkvt + (size_t)2048 * H_, H_, NK);
  transpose_cast<<<dim3(NK / 32, H_ / 32), blk, 0, stream>>>(Wv, Wqkvt + (size_t)3072 * H_, H_, NK);
  transpose_cast<<<dim3(H_ / 32, NQ / 32), blk, 0, stream>>>(Wo, Wot, NQ, H_);

  // fused QKV projection, bf16 out (K=2304 -> NT=36 even; grid 16x16=256)
  if (g_8ph_ok) {
    gemm_8ph<true><<<dim3(QKVW / 256, M / 256), dim3(512), 131072, stream>>>(
        Xb, Wqkvt, QKV16, M, QKVW, H_);
  } else {
    gemm_bt<true><<<dim3(QKVW / 128, M / 128), blk, 0, stream>>>(Xb, Wqkvt, QKV16, M, QKVW, H_);
  }

  rope_inplace<<<dim3(M, 6), blk, 0, stream>>>(QKV16, pos);
  v_prep<<<dim3(S_ / 32, HD_ / 32, B_ * NKV_), blk, 0, stream>>>(QKV16, Vt16);

  // attention: head-pair per block, 512 threads
  attn_mfma<<<dim3(S_ / 64, NKV_, B_), dim3(512), 0, stream>>>(QKV16, Vt16, AOb);

  // output projection, fp32 out: 128^2 tiles -> 576 blocks (saturates 256 CUs)
  gemm_bt<false><<<dim3(H_ / 128, M / 128), blk, 0, stream>>>(AOb, Wot, out, M, H_, NQ);
}

// Round 7
// 353.708 us; speedup vs baseline: 2.0192x; 1.0207x over previous
//
#include <hip/hip_runtime.h>
#include <cmath>

#define B_   2
#define S_   2048
#define H_   2304
#define NH_  8
#define HD_  256
#define NKV_ 4
#define WIN_ 512
#define QKVW 4096   // fused QKV output row width (8+4+4 heads * 256)

typedef unsigned short ushort_t;
typedef __attribute__((ext_vector_type(8))) short bf16x8;     // 8 bf16 = 4 VGPRs
typedef __attribute__((ext_vector_type(4))) float floatx4;

// round-to-nearest-even fp32 -> bf16
__device__ __forceinline__ unsigned short f2bf(float f) {
  unsigned u = __builtin_bit_cast(unsigned, f);
  u += 0x7fff + ((u >> 16) & 1);
  return (unsigned short)(u >> 16);
}
__device__ __forceinline__ float bf2f(ushort_t v) {
  unsigned u = (unsigned)v << 16;
  return __builtin_bit_cast(float, u);
}

// async global->LDS, 16 B per lane. LDS dest = wave-uniform base + lane*16.
__device__ __forceinline__ void gl2lds16(const void* g, void* l) {
  __builtin_amdgcn_global_load_lds(
      (const __attribute__((address_space(1))) unsigned int*)g,
      (__attribute__((address_space(3))) unsigned int*)l, 16, 0, 0);
}

// ---------------------------------------------------------------------------
// Elementwise fp32 -> bf16 cast (4 elems/thread).
// ---------------------------------------------------------------------------
__global__ void cast_bf16(const float* __restrict__ in, ushort_t* __restrict__ out) {
  const int i = blockIdx.x * 256 + threadIdx.x;
  float4 v = ((const float4*)in)[i];
  ushort4 o;
  o.x = f2bf(v.x); o.y = f2bf(v.y); o.z = f2bf(v.z); o.w = f2bf(v.w);
  ((ushort4*)out)[i] = o;
}

// ---------------------------------------------------------------------------
// W[K,N] fp32 -> Wt[N,K] bf16 (32x32 LDS tiles, 256 threads).
// ---------------------------------------------------------------------------
__global__ void transpose_cast(const float* __restrict__ W, ushort_t* __restrict__ Wt,
                               int K, int N) {
  __shared__ float t[32][33];
  const int lx = threadIdx.x & 31, ly = threadIdx.x >> 5;   // ly 0..7
  const int n0 = blockIdx.x * 32, k0 = blockIdx.y * 32;
#pragma unroll
  for (int i = 0; i < 4; ++i)
    t[ly + i * 8][lx] = W[(long long)(k0 + ly + i * 8) * N + n0 + lx];
  __syncthreads();
#pragma unroll
  for (int i = 0; i < 4; ++i)
    Wt[(long long)(n0 + ly + i * 8) * K + k0 + lx] = f2bf(t[lx][ly + i * 8]);
}

// ===========================================================================
// 256x256-tile bf16 MFMA GEMM (m201 8-phase skeleton — kept from r6).
// QKV ~76 µs / 1014 TF / MfmaUtil 42%. Five schedule variants (r1/r2/r4/r5/
// r6) all plateau at 40-42%: per-tile LDS work (~3200 cyc) + MFMA (~2060)
// run near-serialized; further gains need asm-level control. GEMM frozen.
// ===========================================================================
#define RA(base_, qm_) do { \
  _Pragma("unroll") for (int i_ = 0; i_ < 4; ++i_) { \
    const int row_ = wm + (qm_) * 64 + i_ * 16 + l15; \
    _Pragma("unroll") for (int kk_ = 0; kk_ < 2; ++kk_) \
      a[i_][kk_] = *(const bf16x8*)&(base_)[row_ * 64 + (((kk_ * 4 + lq) ^ (l15 & 7)) * 8)]; \
  } \
} while (0)

#define RB(base_, qn_) do { \
  _Pragma("unroll") for (int j_ = 0; j_ < 2; ++j_) { \
    const int row_ = wn + (qn_) * 32 + j_ * 16 + l15; \
    _Pragma("unroll") for (int kk_ = 0; kk_ < 2; ++kk_) \
      b[j_][kk_] = *(const bf16x8*)&(base_)[row_ * 64 + (((kk_ * 4 + lq) ^ (l15 & 7)) * 8)]; \
  } \
} while (0)

#define MFMAQ(qm_, qn_) do { \
  __builtin_amdgcn_s_setprio(1); \
  _Pragma("unroll") for (int kk_ = 0; kk_ < 2; ++kk_) \
  _Pragma("unroll") for (int i_ = 0; i_ < 4; ++i_) \
  _Pragma("unroll") for (int j_ = 0; j_ < 2; ++j_) \
    acc[(qm_) * 4 + i_][(qn_) * 2 + j_] = __builtin_amdgcn_mfma_f32_16x16x32_bf16( \
        a[i_][kk_], b[j_][kk_], acc[(qm_) * 4 + i_][(qn_) * 2 + j_], 0, 0, 0); \
  __builtin_amdgcn_s_setprio(0); \
} while (0)

#define STAGE_A(dst_, gsrc_, t_, qm_) do { \
  _Pragma("unroll") for (int jj_ = 0; jj_ < 2; ++jj_) { \
    const int g_ = w * 2 + jj_; \
    const int tr0_ = ((g_ >> 3) * 128) + (qm_) * 64 + (g_ & 7) * 8; \
    gl2lds16(gsrc_ + (size_t)tr0_ * K + (size_t)(t_) * 64 + laneOff, dst_ + tr0_ * 64); \
  } \
} while (0)

#define STAGE_B(dst_, gsrc_, t_, qn_) do { \
  _Pragma("unroll") for (int jj_ = 0; jj_ < 2; ++jj_) { \
    const int g_ = w * 2 + jj_; \
    const int tr0_ = ((g_ >> 2) * 64) + (qn_) * 32 + (g_ & 3) * 8; \
    gl2lds16(gsrc_ + (size_t)tr0_ * K + (size_t)(t_) * 64 + laneOff, dst_ + tr0_ * 64); \
  } \
} while (0)

#define SB0()   __builtin_amdgcn_sched_barrier(0)
#define BARR()  do { SB0(); __builtin_amdgcn_s_barrier(); } while (0)
#define LGKM0() do { asm volatile("s_waitcnt lgkmcnt(0)" ::: "memory"); SB0(); } while (0)
#define LGKM8() asm volatile("s_waitcnt lgkmcnt(8)" ::: "memory")
#define VM(n_)  asm volatile("s_waitcnt vmcnt(" #n_ ")" ::: "memory")

template <bool OUT_BF16>
__launch_bounds__(512)
__global__ void gemm_8ph(const ushort_t* __restrict__ A,   // [M,K] bf16
                         const ushort_t* __restrict__ Bt,  // [N,K] bf16
                         void* __restrict__ Cv, int M, int N, int K) {
  extern __shared__ __attribute__((aligned(128))) ushort_t smem[];
  const int tid = threadIdx.x, lane = tid & 63, w = tid >> 6;   // w 0..7
  const int wm = (w >> 2) * 128, wn = (w & 3) * 64;
  const int l15 = lane & 15, lq = lane >> 4;

  // T1: XCD-aware swizzle of the linear block id (grid %8 == 0)
  const int nwg  = gridDim.x * gridDim.y;
  const int orig = blockIdx.y * gridDim.x + blockIdx.x;
  const int cpx  = nwg >> 3;
  const int swz  = (orig & 7) * cpx + (orig >> 3);
  const int bx   = swz % gridDim.x, by = swz / gridDim.x;
  const int bm = by * 256, bn = bx * 256;
  const int NT = K >> 6;   // 36 (QKV) — even

  const ushort_t* Ab = A + (size_t)bm * K;
  const ushort_t* Bb = Bt + (size_t)bn * K;
  const size_t laneOff = (size_t)(lane >> 3) * K + (size_t)(((lane & 7) ^ (lane >> 3)) * 8);

  ushort_t* Ae = smem;              // even-tile A (256x64)
  ushort_t* Ao = smem + 16384;      // odd-tile  A
  ushort_t* Be = smem + 32768;      // even-tile B
  ushort_t* Bo = smem + 49152;      // odd-tile  B

  floatx4 acc[8][4] = {};
  bf16x8 a[4][2], b[2][2];

  // prologue: tile0 full (8 loads) + tile1 {A0, B1} (4 loads)
  STAGE_A(Ae, Ab, 0, 0);
  STAGE_B(Be, Bb, 0, 1);
  STAGE_A(Ae, Ab, 0, 1);
  STAGE_B(Be, Bb, 0, 0);
  STAGE_A(Ao, Ab, 1, 0);
  STAGE_B(Bo, Bb, 1, 1);
  VM(4);
  BARR();

  for (int t = 0; t < NT; t += 2) {
    const bool more = (t + 2 < NT);

    // PH1: (t, q00) | stage A1(t+1)
    RA(Ae, 0); RB(Be, 0);
    STAGE_A(Ao, Ab, t + 1, 1);
    LGKM8();
    BARR();
    LGKM0();
    MFMAQ(0, 0);
    BARR();

    // PH2: (t, q01) | stage B0(t+1)
    RB(Be, 1);
    STAGE_B(Bo, Bb, t + 1, 0);
    BARR();
    LGKM0();
    MFMAQ(0, 1);
    BARR();

    // PH3: (t, q11) | stage A0(t+2)
    RA(Ae, 1);
    if (more) STAGE_A(Ae, Ab, t + 2, 0);
    BARR();
    LGKM0();
    MFMAQ(1, 1);
    BARR();

    // PH4: (t, q10) | stage B1(t+2) | vmcnt: tile t+1 complete
    RB(Be, 0);
    if (more) STAGE_B(Be, Bb, t + 2, 1);
    BARR();
    LGKM0();
    MFMAQ(1, 0);
    SB0();
    if (more) { VM(4); } else { VM(0); }
    BARR();

    // PH5: (t+1, q00) | stage A1(t+2)
    RA(Ao, 0); RB(Bo, 0);
    if (more) STAGE_A(Ae, Ab, t + 2, 1);
    LGKM8();
    BARR();
    LGKM0();
    MFMAQ(0, 0);
    BARR();

    // PH6: (t+1, q01) | stage B0(t+2)
    RB(Bo, 1);
    if (more) STAGE_B(Be, Bb, t + 2, 0);
    BARR();
    LGKM0();
    MFMAQ(0, 1);
    BARR();

    // PH7: (t+1, q11) | stage A0(t+3)
    RA(Ao, 1);
    if (more) STAGE_A(Ao, Ab, t + 3, 0);
    BARR();
    LGKM0();
    MFMAQ(1, 1);
    BARR();

    // PH8: (t+1, q10) | stage B1(t+3) | vmcnt: tile t+2 complete
    RB(Bo, 0);
    if (more) STAGE_B(Bo, Bb, t + 3, 1);
    BARR();
    LGKM0();
    MFMAQ(1, 0);
    SB0();
    if (more) { VM(4); } else { VM(0); }
    BARR();
  }

  // epilogue: C write (C/D layout: row = lq*4+rr, col = l15 per 16x16 frag)
  const int r0 = lq * 4;
#pragma unroll
  for (int mf = 0; mf < 8; ++mf)
#pragma unroll
    for (int nf = 0; nf < 4; ++nf) {
      const long long base = (long long)(bm + wm + mf * 16 + r0) * N + bn + wn + nf * 16 + l15;
      if (OUT_BF16) {
        ushort_t* Cp = (ushort_t*)Cv + base;
#pragma unroll
        for (int rr = 0; rr < 4; ++rr) Cp[(long long)rr * N] = f2bf(acc[mf][nf][rr]);
      } else {
        float* Cp = (float*)Cv + base;
#pragma unroll
        for (int rr = 0; rr < 4; ++rr) Cp[(long long)rr * N] = acc[mf][nf][rr];
      }
    }
}

#undef RA
#undef RB
#undef MFMAQ
#undef STAGE_A
#undef STAGE_B
#undef SB0
#undef BARR
#undef LGKM0
#undef LGKM8
#undef VM

// ---------------------------------------------------------------------------
// 128x128 GEMM (register-double-buffered) — output projection (576 blocks
// saturate all CUs) and fallback.
// ---------------------------------------------------------------------------
template <bool OUT_BF16>
__launch_bounds__(256)
__global__ void gemm_bt(const ushort_t* __restrict__ A,   // [M,K] bf16
                        const ushort_t* __restrict__ Bt,  // [N,K] bf16
                        void* __restrict__ Cv, int M, int N, int K) {
  __shared__ ushort_t As[128 * 64];
  __shared__ ushort_t Bs[128 * 64];
  const int tid = threadIdx.x, lane = tid & 63, wid = tid >> 6;
  const int bm = blockIdx.y * 128, bn = blockIdx.x * 128;
  const int wm = (wid >> 1) * 64, wn = (wid & 1) * 64;

  floatx4 acc[4][4] = {};

  const int r  = tid >> 1;
  const int cp = (tid & 1) * 4;
  const int wkey = r & 7;
  const ushort_t* Ap = A  + (long long)(bm + r) * K + cp * 8;
  const ushort_t* Bp = Bt + (long long)(bn + r) * K + cp * 8;
  ushort_t* Aw = &As[r * 64];
  ushort_t* Bw = &Bs[r * 64];

  const int l15 = lane & 15, lq = lane >> 4;
  const int rkey = l15 & 7;

  bf16x8 ar[4], br[4];
#pragma unroll
  for (int i = 0; i < 4; ++i) {
    ar[i] = *(const bf16x8*)(Ap + i * 8);
    br[i] = *(const bf16x8*)(Bp + i * 8);
  }

  for (int k0 = 0; k0 < K; k0 += 64) {
    __syncthreads();
#pragma unroll
    for (int i = 0; i < 4; ++i) {
      *(bf16x8*)&Aw[((cp + i) ^ wkey) * 8] = ar[i];
      *(bf16x8*)&Bw[((cp + i) ^ wkey) * 8] = br[i];
    }
    __syncthreads();

    if (k0 + 64 < K) {
      const int kn = k0 + 64;
#pragma unroll
      for (int i = 0; i < 4; ++i) {
        ar[i] = *(const bf16x8*)(Ap + kn + i * 8);
        br[i] = *(const bf16x8*)(Bp + kn + i * 8);
      }
    }

#pragma unroll
    for (int kk = 0; kk < 2; ++kk) {
      bf16x8 af[4], bfr[4];
#pragma unroll
      for (int i = 0; i < 4; ++i) {
        af[i]  = *(const bf16x8*)&As[(wm + i * 16 + l15) * 64 + ((kk * 4 + lq) ^ rkey) * 8];
        bfr[i] = *(const bf16x8*)&Bs[(wn + i * 16 + l15) * 64 + ((kk * 4 + lq) ^ rkey) * 8];
      }
#pragma unroll
      for (int i = 0; i < 4; ++i)
#pragma unroll
        for (int j = 0; j < 4; ++j)
          acc[i][j] = __builtin_amdgcn_mfma_f32_16x16x32_bf16(af[i], bfr[j], acc[i][j], 0, 0, 0);
    }
  }

  const int r0 = lq * 4, c0 = l15;
#pragma unroll
  for (int i = 0; i < 4; ++i)
#pragma unroll
    for (int j = 0; j < 4; ++j) {
      const long long base = (long long)(bm + wm + i * 16 + r0) * N + bn + wn + j * 16 + c0;
      if (OUT_BF16) {
        ushort_t* Cp = (ushort_t*)Cv + base;
#pragma unroll
        for (int rr = 0; rr < 4; ++rr) Cp[(long long)rr * N] = f2bf(acc[i][j][rr]);
      } else {
        float* Cp = (float*)Cv + base;
#pragma unroll
        for (int rr = 0; rr < 4; ++rr) Cp[(long long)rr * N] = acc[i][j][rr];
      }
    }
}

// ---------------------------------------------------------------------------
// In-place RoPE on QKV16 [B*S][4096] bf16 (Q cols 0..2047, K cols 2048..3071).
// Also folds the 1/16 attention scale into Q. V region untouched.
// ---------------------------------------------------------------------------
__global__ void rope_inplace(ushort_t* __restrict__ QKV16, const int* __restrict__ pos) {
  const int bs  = blockIdx.x;
  const int gid = blockIdx.y * 256 + threadIdx.x;
  const int head = gid >> 7;          // 0..11
  const int d    = gid & 127;
  const float pp   = (float)pos[bs];
  const float invf = __expf(-(float)d * (9.210340371976184f / 128.0f));
  const float ang  = pp * invf;
  float sn, cc;
  __sincosf(ang, &sn, &cc);
  ushort_t* base = QKV16 + (size_t)bs * QKVW + head * HD_;
  const float x1 = bf2f(base[d]);
  const float x2 = bf2f(base[d + 128]);
  float o1 = x1 * cc - x2 * sn;
  float o2 = x2 * cc + x1 * sn;
  if (head < NH_) { o1 *= 0.0625f; o2 *= 0.0625f; }   // fold 1/sqrt(256) into Q
  base[d]       = f2bf(o1);
  base[d + 128] = f2bf(o2);
}

// ---------------------------------------------------------------------------
// V transpose: QKV16 V region -> Vt16 [B][NKV][256][S] bf16.
// ---------------------------------------------------------------------------
__global__ void v_prep(const ushort_t* __restrict__ QKV16, ushort_t* __restrict__ Vt16) {
  __shared__ ushort_t tile[32][33];
  const int k0 = blockIdx.x * 32, d0 = blockIdx.y * 32;
  const int b = blockIdx.z >> 2, hk = blockIdx.z & 3;
  const int lx = threadIdx.x & 31, ly = threadIdx.x >> 5;
#pragma unroll
  for (int i = 0; i < 4; ++i)
    tile[ly + 8 * i][lx] =
        QKV16[(size_t)(b * S_ + k0 + ly + 8 * i) * QKVW + 3072 + hk * HD_ + d0 + lx];
  __syncthreads();
#pragma unroll
  for (int i = 0; i < 4; ++i)
    Vt16[((size_t)(b * NKV_ + hk) * HD_ + d0 + ly + 8 * i) * S_ + k0 + lx] =
        tile[lx][ly + 8 * i];
}

// ===========================================================================
// MFMA flash attention v2: K/V DOUBLE-BUFFERED staging (T14/T3 minimum
// pipeline). Grid = 1 block/CU => no block-level TLP; the old kernel's
// sync-stage-sync-compute loop exposed full staging latency each of ~18
// iterations. Now: prologue-stage buf0; per iter {issue stage kb+32 into
// other buf | compute current | barrier}. Barriers 2->1 per iter.
// WAR: reads of buf b are consumed (lgkm-waited before MFMA) before the
// iteration-end barrier; b is restaged only AFTER that barrier (next iter).
// RAW: __syncthreads' implicit vmcnt(0) drain covers the issued stage.
// Dynamic LDS 74.2 KB (needs opt-in); static single-buffer fallback kept.
// ===========================================================================
#define ATTN_STG_KV(KD_, VD_, kb_) do { \
  _Pragma("unroll") for (int i_ = 0; i_ < 2; ++i_) { \
    const int kl_ = w * 4 + 2 * i_ + ksr; \
    gl2lds16(Kh + (size_t)((kb_) + kl_) * QKVW + (ksp ^ (kl_ & 31)) * 8, \
             (KD_) + (w * 4 + 2 * i_) * 256); \
  } \
  _Pragma("unroll") for (int i_ = 0; i_ < 2; ++i_) { \
    const int dl_ = w * 32 + 16 * i_ + vsr; \
    gl2lds16(Vh + (size_t)dl_ * S_ + (kb_) + (vsp ^ ((dl_ >> 1) & 3)) * 8, \
             (VD_) + (w * 32 + 16 * i_) * 32); \
  } \
} while (0)

#define ATTN_BODY(Kc_, Vc_) do { \
  if (kb <= qw + 15 && kb + 31 >= qw - (WIN_ - 1)) { \
    ushort_t* Pw = PsA + w * 512; \
    _Pragma("unroll") for (int kt = 0; kt < 2; ++kt) { \
      floatx4 sacc = {}; \
      const int keyl = kt * 16 + l15; \
      const int krow = keyl * 256; \
      const int ksw = keyl & 31; \
      __builtin_amdgcn_s_setprio(1); \
      _Pragma("unroll") for (int kd = 0; kd < 8; ++kd) { \
        bf16x8 bk = *(const bf16x8*)&(Kc_)[krow + ((kd * 4 + lq) ^ ksw) * 8]; \
        sacc = __builtin_amdgcn_mfma_f32_16x16x32_bf16(afq[kd], bk, sacc, 0, 0, 0); \
      } \
      __builtin_amdgcn_s_setprio(0); \
      const int keyg = kb + keyl; \
      _Pragma("unroll") for (int rr = 0; rr < 4; ++rr) { \
        const int qg = qw + lq * 4 + rr; \
        const float t = __expf(sacc[rr] * 0.04f); \
        const float L = 50.f - __fdividef(100.f, t + 1.f); \
        float p = __expf(L); \
        p = (keyg <= qg && keyg >= qg - (WIN_ - 1)) ? p : 0.f; \
        rs[rr] += p; \
        const int ql = lq * 4 + rr; \
        const int ch = kt * 2 + (l15 >> 3); \
        Pw[ql * 32 + ((ch ^ ((ql >> 1) & 3)) * 8) + (l15 & 7)] = f2bf(p); \
      } \
    } \
    asm volatile("s_waitcnt lgkmcnt(0)" ::: "memory"); \
    const bf16x8 bp = *(const bf16x8*)&Pw[l15 * 32 + ((lq ^ ((l15 >> 1) & 3)) * 8)]; \
    const int vsw = (l15 >> 1) & 3; \
    __builtin_amdgcn_s_setprio(1); \
    _Pragma("unroll") for (int tt = 0; tt < 16; ++tt) { \
      bf16x8 av = *(const bf16x8*)&(Vc_)[(tt * 16 + l15) * 32 + ((lq ^ vsw) * 8)]; \
      acc[tt] = __builtin_amdgcn_mfma_f32_16x16x32_bf16(av, bp, acc[tt], 0, 0, 0); \
    } \
    __builtin_amdgcn_s_setprio(0); \
  } \
} while (0)

__launch_bounds__(512)
__global__ void attn_mfma(const ushort_t* __restrict__ QKV16,  // [B*S][4096]
                          const ushort_t* __restrict__ Vt16,   // [B][NKV][256][S]
                          ushort_t* __restrict__ AOb) {        // [B][S][NH][256]
  extern __shared__ __attribute__((aligned(128))) ushort_t alds[];
  ushort_t* Ks0 = alds;                 // 32*256
  ushort_t* Ks1 = alds + 8192;
  ushort_t* Vt0 = alds + 16384;         // 256*32
  ushort_t* Vt1 = alds + 24576;
  ushort_t* PsA = alds + 32768;         // 8 * 512
  float*    rsb = (float*)(alds + 32768 + 4096);   // 8*16 floats

  const int lane = threadIdx.x & 63, w = threadIdx.x >> 6;   // w 0..7
  const int l15 = lane & 15, lq = lane >> 4;
  const int qb = blockIdx.x * 64;
  const int hp = blockIdx.y, b = blockIdx.z;                 // hp = hk
  const int h  = hp * 2 + (w >> 2);
  const int hw = w & 3;                                      // wave-in-head

  const ushort_t* Qh = QKV16 + (size_t)b * S_ * QKVW + h * HD_;
  const ushort_t* Kh = QKV16 + (size_t)b * S_ * QKVW + 2048 + hp * HD_;
  const ushort_t* Vh = Vt16 + ((size_t)(b * NKV_ + hp) * HD_) * S_;

  const int qw = qb + hw * 16;   // wave's first query

  bf16x8 afq[8];
  {
    const ushort_t* qr = Qh + (size_t)(qw + l15) * QKVW + lq * 8;
#pragma unroll
    for (int kd = 0; kd < 8; ++kd) afq[kd] = *(const bf16x8*)(qr + kd * 32);
  }

  floatx4 acc[16] = {};
  float rs[4] = {0.f, 0.f, 0.f, 0.f};

  int kb0 = qb - (WIN_ - 1);
  if (kb0 < 0) kb0 = 0;
  kb0 &= ~31;
  const int kbEnd = qb + 64;

  const int ksp = lane & 31, ksr = lane >> 5;
  const int vsp = lane & 3,  vsr = lane >> 2;

  // prologue: stage first tile into buf0
  ATTN_STG_KV(Ks0, Vt0, kb0);
  __syncthreads();   // implicit vmcnt(0) drain: buf0 landed

  int tog = 0;
  for (int kb = kb0; kb < kbEnd; kb += 32) {
    ushort_t* Kc = tog ? Ks1 : Ks0;
    ushort_t* Vc = tog ? Vt1 : Vt0;
    ushort_t* Kn = tog ? Ks0 : Ks1;
    ushort_t* Vn = tog ? Vt0 : Vt1;
    if (kb + 32 < kbEnd) ATTN_STG_KV(Kn, Vn, kb + 32);   // issue, no wait
    ATTN_BODY(Kc, Vc);                                   // compute current
    __syncthreads();   // drains vmcnt (next buf ready) + all reads done
    tog ^= 1;
  }

#pragma unroll
  for (int rr = 0; rr < 4; ++rr) {
    rs[rr] += __shfl_xor(rs[rr], 1, 64);
    rs[rr] += __shfl_xor(rs[rr], 2, 64);
    rs[rr] += __shfl_xor(rs[rr], 4, 64);
    rs[rr] += __shfl_xor(rs[rr], 8, 64);
  }
  if (l15 == 0) {
#pragma unroll
    for (int rr = 0; rr < 4; ++rr) rsb[w * 16 + lq * 4 + rr] = rs[rr];
  }
  asm volatile("s_waitcnt lgkmcnt(0)" ::: "memory");
  __builtin_amdgcn_wave_barrier();
  const float inv = 1.0f / rsb[w * 16 + l15];

  const size_t ob = ((size_t)(b * S_ + qw + l15) * NH_ + h) * HD_;
#pragma unroll
  for (int t = 0; t < 16; ++t) {
    ushort4 o;
    o.x = f2bf(acc[t][0] * inv);
    o.y = f2bf(acc[t][1] * inv);
    o.z = f2bf(acc[t][2] * inv);
    o.w = f2bf(acc[t][3] * inv);
    *(ushort4*)&AOb[ob + t * 16 + lq * 4] = o;
  }
}

// --------- static single-buffer fallback (original) ------------------------
__launch_bounds__(512)
__global__ void attn_mfma_s(const ushort_t* __restrict__ QKV16,
                            const ushort_t* __restrict__ Vt16,
                            ushort_t* __restrict__ AOb) {
  __shared__ ushort_t Ks[32 * 256];
  __shared__ ushort_t Vts[256 * 32];
  __shared__ ushort_t PsS[8][16 * 32];
  __shared__ float rsbS[8][16];

  const int lane = threadIdx.x & 63, w = threadIdx.x >> 6;
  const int l15 = lane & 15, lq = lane >> 4;
  const int qb = blockIdx.x * 64;
  const int hp = blockIdx.y, b = blockIdx.z;
  const int h  = hp * 2 + (w >> 2);
  const int hw = w & 3;

  const ushort_t* Qh = QKV16 + (size_t)b * S_ * QKVW + h * HD_;
  const ushort_t* Kh = QKV16 + (size_t)b * S_ * QKVW + 2048 + hp * HD_;
  const ushort_t* Vh = Vt16 + ((size_t)(b * NKV_ + hp) * HD_) * S_;

  const int qw = qb + hw * 16;

  bf16x8 afq[8];
  {
    const ushort_t* qr = Qh + (size_t)(qw + l15) * QKVW + lq * 8;
#pragma unroll
    for (int kd = 0; kd < 8; ++kd) afq[kd] = *(const bf16x8*)(qr + kd * 32);
  }

  floatx4 acc[16] = {};
  float rs[4] = {0.f, 0.f, 0.f, 0.f};

  int kb0 = qb - (WIN_ - 1);
  if (kb0 < 0) kb0 = 0;
  kb0 &= ~31;

  const int ksp = lane & 31, ksr = lane >> 5;
  const int vsp = lane & 3,  vsr = lane >> 2;

  for (int kb = kb0; kb < qb + 64; kb += 32) {
    __syncthreads();
    ATTN_STG_KV(Ks, Vts, kb);
    __syncthreads();
    ushort_t* PsA = &PsS[0][0];
    ATTN_BODY(Ks, Vts);
  }

#pragma unroll
  for (int rr = 0; rr < 4; ++rr) {
    rs[rr] += __shfl_xor(rs[rr], 1, 64);
    rs[rr] += __shfl_xor(rs[rr], 2, 64);
    rs[rr] += __shfl_xor(rs[rr], 4, 64);
    rs[rr] += __shfl_xor(rs[rr], 8, 64);
  }
  if (l15 == 0) {
#pragma unroll
    for (int rr = 0; rr < 4; ++rr) rsbS[w][lq * 4 + rr] = rs[rr];
  }
  asm volatile("s_waitcnt lgkmcnt(0)" ::: "memory");
  __builtin_amdgcn_wave_barrier();
  const float inv = 1.0f / rsbS[w][l15];

  const size_t ob = ((size_t)(b * S_ + qw + l15) * NH_ + h) * HD_;
#pragma unroll
  for (int t = 0; t < 16; ++t) {
    ushort4 o;
    o.x = f2bf(acc[t][0] * inv);
    o.y = f2bf(acc[t][1] * inv);
    o.z = f2bf(acc[t][2] * inv);
    o.w = f2bf(acc[t][3] * inv);
    *(ushort4*)&AOb[ob + t * 16 + lq * 4] = o;
  }
}

#undef ATTN_STG_KV
#undef ATTN_BODY

// ---------------------------------------------------------------------------
extern "C" void kernel_launch(void* const* d_in, const int* in_sizes, int n_in,
                              void* d_out, int out_size, void* d_ws, size_t ws_size,
                              hipStream_t stream) {
  const float* X   = (const float*)d_in[0];
  const int*   pos = (const int*)d_in[2];
  const float* Wq  = (const float*)d_in[3];   // [2304, 2048]
  const float* Wk  = (const float*)d_in[4];   // [2304, 1024]
  const float* Wv  = (const float*)d_in[5];   // [2304, 1024]
  const float* Wo  = (const float*)d_in[6];   // [2048, 2304]
  float* out = (float*)d_out;

  const int M  = B_ * S_;        // 4096
  const int NQ = NH_ * HD_;      // 2048
  const int NK = NKV_ * HD_;     // 1024

  char* w = (char*)d_ws;
  ushort_t* QKV16 = (ushort_t*)w;  w += (size_t)M * QKVW * 2;          // 32 MB
  ushort_t* Xb    = (ushort_t*)w;  w += (size_t)M * H_ * 2;            // 18 MB
  ushort_t* Wqkvt = (ushort_t*)w;  w += (size_t)QKVW * H_ * 2;         // 18 MB
  ushort_t* Wot   = (ushort_t*)w;  w += (size_t)H_ * NQ * 2;           // 9.4 MB
  ushort_t* Vt16  = (ushort_t*)w;  w += (size_t)B_ * NKV_ * S_ * HD_ * 2;  // 8 MB
  ushort_t* AOb   = (ushort_t*)w;  w += (size_t)M * NQ * 2;            // 16 MB

  // dynamic-LDS opt-ins (host-side, capture-safe)
  static bool g_init = false, g_8ph_ok = false, g_attn_ok = false;
  if (!g_init) {
    hipError_t e1 = hipFuncSetAttribute(
        reinterpret_cast<const void*>(&gemm_8ph<true>),
        hipFuncAttributeMaxDynamicSharedMemorySize, 131072);
    g_8ph_ok = (e1 == hipSuccess);
    hipError_t e2 = hipFuncSetAttribute(
        reinterpret_cast<const void*>(&attn_mfma),
        hipFuncAttributeMaxDynamicSharedMemorySize, 74240);
    g_attn_ok = (e2 == hipSuccess);
    g_init = true;
  }

  dim3 blk(256);

  cast_bf16<<<(M * H_) / 1024, blk, 0, stream>>>(X, Xb);
  // concatenated transposed QKV weights: rows [0,2048)=Wq^T, [2048,3072)=Wk^T, [3072,4096)=Wv^T
  transpose_cast<<<dim3(NQ / 32, H_ / 32), blk, 0, stream>>>(Wq, Wqkvt, H_, NQ);
  transpose_cast<<<dim3(NK / 32, H_ / 32), blk, 0, stream>>>(Wk, Wqkvt + (size_t)2048 * H_, H_, NK);
  transpose_cast<<<dim3(NK / 32, H_ / 32), blk, 0, stream>>>(Wv, Wqkvt + (size_t)3072 * H_, H_, NK);
  transpose_cast<<<dim3(H_ / 32, NQ / 32), blk, 0, stream>>>(Wo, Wot, NQ, H_);

  // fused QKV projection, bf16 out (K=2304 -> NT=36 even; grid 16x16=256)
  if (g_8ph_ok) {
    gemm_8ph<true><<<dim3(QKVW / 256, M / 256), dim3(512), 131072, stream>>>(
        Xb, Wqkvt, QKV16, M, QKVW, H_);
  } else {
    gemm_bt<true><<<dim3(QKVW / 128, M / 128), blk, 0, stream>>>(Xb, Wqkvt, QKV16, M, QKVW, H_);
  }

  rope_inplace<<<dim3(M, 6), blk, 0, stream>>>(QKV16, pos);
  v_prep<<<dim3(S_ / 32, HD_ / 32, B_ * NKV_), blk, 0, stream>>>(QKV16, Vt16);

  // attention: head-pair per block, 512 threads; K/V double-buffered
  if (g_attn_ok) {
    attn_mfma<<<dim3(S_ / 64, NKV_, B_), dim3(512), 74240, stream>>>(QKV16, Vt16, AOb);
  } else {
    attn_mfma_s<<<dim3(S_ / 64, NKV_, B_), dim3(512), 0, stream>>>(QKV16, Vt16, AOb);
  }

  // output projection, fp32 out: 128^2 tiles -> 576 blocks (saturates 256 CUs)
  gemm_bt<false><<<dim3(H_ / 128, M / 128), blk, 0, stream>>>(AOb, Wot, out, M, H_, NQ);
}